// Round 1
// 778.973 us; speedup vs baseline: 1.0095x; 1.0095x over previous
//
#include <hip/hip_runtime.h>
#include <stdint.h>

// Problem geometry (fixed by reference): a = [64,3,768,768] f32
#define BATCH 64
#define PIX   589824      // 768*768 pixels per image
#define PIX4  147456      // PIX/4 (float4 units)
#define IMG3  442368      // 3*PIX4 (float4 stride per image in a)
#define N_TOT 37748736    // BATCH*PIX  (output elements)
#define N4    9437184     // N_TOT/4
#define BPI   144         // K1 blocks per image
#define NPART (BATCH*BPI) // 9216 partials

typedef float f32x4 __attribute__((ext_vector_type(4)));

// Module-scope device buffers: d_ws is NOT used at all this round.
// Every element is written before it is read within a single kernel_launch
// (K1 writes all of g_gray4/g_p* -> K2 writes all of g_stats -> K3 reads),
// so there is no cross-iteration state dependence.
__device__ f32x4  g_gray4[N4];     // 151 MB gray buffer (.bss)
__device__ float  g_pmin[NPART];
__device__ float  g_pmax[NPART];
__device__ float  g_psum[NPART];
__device__ float2 g_stats[BATCH];

__device__ __forceinline__ uint32_t rotl32(uint32_t x, int r) {
    return (x << r) | (x >> (32 - r));
}

// Threefry-2x32, 20 rounds, key = (0,1)  [jax.random.key(1)]
__device__ __forceinline__ void threefry01(uint32_t x0, uint32_t x1,
                                           uint32_t& o0, uint32_t& o1) {
    const uint32_t ks0 = 0u, ks1 = 1u, ks2 = 0x1BD11BDBu; // 0x1BD11BDA ^ 0 ^ 1
    x0 += ks0; x1 += ks1;
#define RND(r) { x0 += x1; x1 = rotl32(x1, (r)); x1 ^= x0; }
    RND(13) RND(15) RND(26) RND(6)   x0 += ks1; x1 += ks2 + 1u;
    RND(17) RND(29) RND(16) RND(24)  x0 += ks2; x1 += ks0 + 2u;
    RND(13) RND(15) RND(26) RND(6)   x0 += ks0; x1 += ks1 + 3u;
    RND(17) RND(29) RND(16) RND(24)  x0 += ks1; x1 += ks2 + 4u;
    RND(13) RND(15) RND(26) RND(6)   x0 += ks2; x1 += ks0 + 5u;
#undef RND
    o0 = x0; o1 = x1;
}

// Partitionable threefry 32-bit draw for element index i (< 2^32):
// counter = (hi=0, lo=i); bits = word0 ^ word1.
__device__ __forceinline__ uint32_t jax_bits32(uint32_t i) {
    uint32_t w0, w1;
    threefry01(0u, i, w0, w1);
    return w0 ^ w1;
}

// bits -> uniform[-0.99999994, 1) -> 0.01 * sqrt(2)*erfinv(u)  (XLA-matching)
__device__ __forceinline__ float noise_from_bits(uint32_t bits) {
    float f = __uint_as_float((bits >> 9) | 0x3f800000u) - 1.0f; // [0,1)
    const float LO = __uint_as_float(0xBF7FFFFFu);               // nextafter(-1,0)
    // (maxval-minval) rounds to exactly 2.0f in f32
    float u = fmaxf(LO, fmaf(f, 2.0f, LO));
    // XLA ErfInv32 (Giles): w = -log1p(-u*u)
    float w  = -log1pf(-u * u);
    float ws = w - 2.5f;
    float wb = sqrtf(w) - 3.0f;
    float p1 = 2.81022636e-08f;
    p1 = fmaf(p1, ws, 3.43273939e-07f);
    p1 = fmaf(p1, ws, -3.5233877e-06f);
    p1 = fmaf(p1, ws, -4.39150654e-06f);
    p1 = fmaf(p1, ws, 0.00021858087f);
    p1 = fmaf(p1, ws, -0.00125372503f);
    p1 = fmaf(p1, ws, -0.00417768164f);
    p1 = fmaf(p1, ws, 0.246640727f);
    p1 = fmaf(p1, ws, 1.50140941f);
    float p2 = -0.000200214257f;
    p2 = fmaf(p2, wb, 0.000100950558f);
    p2 = fmaf(p2, wb, 0.00134934322f);
    p2 = fmaf(p2, wb, -0.00367342844f);
    p2 = fmaf(p2, wb, 0.00573950773f);
    p2 = fmaf(p2, wb, -0.0076224613f);
    p2 = fmaf(p2, wb, 0.00943887047f);
    p2 = fmaf(p2, wb, 1.00167406f);
    p2 = fmaf(p2, wb, 2.83297682f);
    float p = (w < 5.0f) ? p1 : p2;
    return 0.01f * 1.41421354f * (p * u);
}

// K1: channel mean + per-block {min,max,sum} partials; store g to module global.
// a is read once ever -> nontemporal loads (keep g resident in L2/L3 instead).
__global__ __launch_bounds__(256) void k1_reduce(const float* __restrict__ a) {
    const int b = blockIdx.y;
    const int tid = threadIdx.x;
    const f32x4* a4 = (const f32x4*)a;
    const int base = b * IMG3;
    const int chunk = blockIdx.x * (256 * 4);
    const float inv3 = 1.0f / 3.0f;
    float mn = 1e30f, mx = -1e30f, sm = 0.0f;
#pragma unroll
    for (int j = 0; j < 4; ++j) {
        int p4 = chunk + j * 256 + tid;
        f32x4 c0 = __builtin_nontemporal_load(&a4[base + p4]);
        f32x4 c1 = __builtin_nontemporal_load(&a4[base + PIX4 + p4]);
        f32x4 c2 = __builtin_nontemporal_load(&a4[base + 2 * PIX4 + p4]);
        f32x4 g = (c0 + c1 + c2) * inv3;   // elementwise, same rounding as before
        g_gray4[b * PIX4 + p4] = g;        // plain store: want this cached for K3
        mn = fminf(mn, fminf(fminf(g.x, g.y), fminf(g.z, g.w)));
        mx = fmaxf(mx, fmaxf(fmaxf(g.x, g.y), fmaxf(g.z, g.w)));
        sm += (g.x + g.y) + (g.z + g.w);
    }
#pragma unroll
    for (int off = 32; off; off >>= 1) {
        mn = fminf(mn, __shfl_down(mn, off));
        mx = fmaxf(mx, __shfl_down(mx, off));
        sm += __shfl_down(sm, off);
    }
    __shared__ float smn[4], smx[4], ssm[4];
    int wave = tid >> 6, lane = tid & 63;
    if (lane == 0) { smn[wave] = mn; smx[wave] = mx; ssm[wave] = sm; }
    __syncthreads();
    if (tid == 0) {
        mn = fminf(fminf(smn[0], smn[1]), fminf(smn[2], smn[3]));
        mx = fmaxf(fmaxf(smx[0], smx[1]), fmaxf(smx[2], smx[3]));
        sm = (ssm[0] + ssm[1]) + (ssm[2] + ssm[3]);
        int pi = b * BPI + blockIdx.x;
        g_pmin[pi] = mn; g_pmax[pi] = mx; g_psum[pi] = sm;
    }
}

// K2: fold 144 partials per image -> per-image (scale, bias) with invert folded in.
__global__ __launch_bounds__(64) void k2_finalize() {
    const int b = blockIdx.x;
    const int t = threadIdx.x;
    float mn = 1e30f, mx = -1e30f;
    double sm = 0.0;
    for (int k = t; k < BPI; k += 64) {
        mn = fminf(mn, g_pmin[b * BPI + k]);
        mx = fmaxf(mx, g_pmax[b * BPI + k]);
        sm += (double)g_psum[b * BPI + k];
    }
#pragma unroll
    for (int off = 32; off; off >>= 1) {
        mn = fminf(mn, __shfl_down(mn, off));
        mx = fmaxf(mx, __shfl_down(mx, off));
        sm += __shfl_down(sm, off);
    }
    if (t == 0) {
        float div = fmaxf(0.5f, mx - mn);
        float mean_norm = (float)((sm / (double)PIX - (double)mn) / (double)div);
        float s, tt;
        if (mean_norm > 0.5f) { s = -1.0f / div; tt = 1.0f + mn / div; }
        else                  { s =  1.0f / div; tt = -mn / div; }
        g_stats[b] = make_float2(s, tt);
    }
}

// K3: out = clip(s*g + t + noise, 0, 1), one float4 per thread.
// Processes images in REVERSE order (63 -> 0): K1 wrote g ascending, so the
// Infinity-Cache-resident tail images are consumed first while still hot.
__global__ __launch_bounds__(256) void k3_apply(float* __restrict__ out) {
    const int gt0 = blockIdx.x * 256 + threadIdx.x;   // f4 index in [0, N4)
    const int b0 = gt0 / PIX4;                        // blocks never straddle images
    const int b  = (BATCH - 1) - b0;                  // reversed image order
    const int gt = b * PIX4 + (gt0 - b0 * PIX4);      // f4 index within reversed image
    const float2 st = g_stats[b];

    f32x4 g = g_gray4[gt];

    const uint32_t i = (uint32_t)gt * 4u;
    float n0 = noise_from_bits(jax_bits32(i + 0u));
    float n1 = noise_from_bits(jax_bits32(i + 1u));
    float n2 = noise_from_bits(jax_bits32(i + 2u));
    float n3 = noise_from_bits(jax_bits32(i + 3u));

    f32x4 o;
    o.x = fminf(fmaxf(fmaf(st.x, g.x, st.y) + n0, 0.0f), 1.0f);
    o.y = fminf(fmaxf(fmaf(st.x, g.y, st.y) + n1, 0.0f), 1.0f);
    o.z = fminf(fmaxf(fmaf(st.x, g.z, st.y) + n2, 0.0f), 1.0f);
    o.w = fminf(fmaxf(fmaf(st.x, g.w, st.y) + n3, 0.0f), 1.0f);

    // out is never re-read: nontemporal store, keep caches for g.
    __builtin_nontemporal_store(o, &((f32x4*)out)[gt]);
}

extern "C" void kernel_launch(void* const* d_in, const int* in_sizes, int n_in,
                              void* d_out, int out_size, void* d_ws, size_t ws_size,
                              hipStream_t stream) {
    const float* a = (const float*)d_in[0];
    float* out = (float*)d_out;
    (void)d_ws; (void)ws_size;   // workspace intentionally unused this round

    k1_reduce<<<dim3(BPI, BATCH), 256, 0, stream>>>(a);
    k2_finalize<<<BATCH, 64, 0, stream>>>();
    k3_apply<<<N4 / 256, 256, 0, stream>>>(out);
}